// Round 1
// baseline (22290.681 us; speedup 1.0000x reference)
//
#include <hip/hip_runtime.h>
#include <hip/hip_bf16.h>

#define N_NODES 100000
#define N_FEAT  512
#define N_HID   256
#define N_EDGES 3200000

// ---------------- FC GEMM: h[n,j] = sum_f X[n,f]*W[j,f] + b[j], out bf16 ----
// 64x64 tile, 256 threads, each thread 4x4 micro-tile. LDS stored transposed
// ([k][row]) so fragment reads are float4 (ds_read_b128).
#define TILE 64
#define KT   16

__global__ __launch_bounds__(256) void gemm_fc(
    const float* __restrict__ X, const float* __restrict__ W,
    const float* __restrict__ bias, __hip_bfloat16* __restrict__ Hout, int N)
{
    __shared__ float Xs[KT][TILE + 4];
    __shared__ float Ws[KT][TILE + 4];

    const int tid = threadIdx.x;
    const int tx = tid & 15;   // hid micro index
    const int ty = tid >> 4;   // node micro index
    const int n0 = blockIdx.x * TILE;
    const int j0 = blockIdx.y * TILE;

    const int lrow = tid >> 2;       // 0..63
    const int lk   = (tid & 3) * 4;  // 0,4,8,12

    const int gn = n0 + lrow;
    const bool xok = gn < N;
    const float* xp = X + (size_t)(xok ? gn : 0) * N_FEAT + lk;
    const float* wp = W + (size_t)(j0 + lrow) * N_FEAT + lk;

    float acc[4][4] = {{0.f}};

    for (int k0 = 0; k0 < N_FEAT; k0 += KT) {
        float4 xv = xok ? *(const float4*)(xp + k0) : make_float4(0.f, 0.f, 0.f, 0.f);
        float4 wv = *(const float4*)(wp + k0);
        __syncthreads();
        Xs[lk + 0][lrow] = xv.x; Xs[lk + 1][lrow] = xv.y;
        Xs[lk + 2][lrow] = xv.z; Xs[lk + 3][lrow] = xv.w;
        Ws[lk + 0][lrow] = wv.x; Ws[lk + 1][lrow] = wv.y;
        Ws[lk + 2][lrow] = wv.z; Ws[lk + 3][lrow] = wv.w;
        __syncthreads();
        #pragma unroll
        for (int kk = 0; kk < KT; kk++) {
            const float4 av = *(const float4*)(&Xs[kk][ty * 4]);
            const float4 bv = *(const float4*)(&Ws[kk][tx * 4]);
            const float a0 = av.x, a1 = av.y, a2 = av.z, a3 = av.w;
            const float b0 = bv.x, b1 = bv.y, b2 = bv.z, b3 = bv.w;
            acc[0][0] += a0 * b0; acc[0][1] += a0 * b1; acc[0][2] += a0 * b2; acc[0][3] += a0 * b3;
            acc[1][0] += a1 * b0; acc[1][1] += a1 * b1; acc[1][2] += a1 * b2; acc[1][3] += a1 * b3;
            acc[2][0] += a2 * b0; acc[2][1] += a2 * b1; acc[2][2] += a2 * b2; acc[2][3] += a2 * b3;
            acc[3][0] += a3 * b0; acc[3][1] += a3 * b1; acc[3][2] += a3 * b2; acc[3][3] += a3 * b3;
        }
    }

    #pragma unroll
    for (int i = 0; i < 4; i++) {
        const int gn2 = n0 + ty * 4 + i;
        if (gn2 >= N) continue;
        #pragma unroll
        for (int j = 0; j < 4; j++) {
            const int gj = j0 + tx * 4 + j;
            Hout[(size_t)gn2 * N_HID + gj] = __float2bfloat16(acc[i][j] + bias[gj]);
        }
    }
}

// ---------------- SpMM: agg[row] += ev * h_bf16[col], one wave per edge -----
__global__ __launch_bounds__(256) void spmm_scatter(
    const __hip_bfloat16* __restrict__ H, const int* __restrict__ rows,
    const int* __restrict__ cols, const float* __restrict__ ev,
    float* __restrict__ agg, int E)
{
    const int e = blockIdx.x * 4 + (threadIdx.x >> 6);
    if (e >= E) return;
    const int lane = threadIdx.x & 63;
    const int r = rows[e];
    const int c = cols[e];
    const float v = ev[e];

    const uint2 raw = *(const uint2*)((const unsigned short*)H + (size_t)c * N_HID + lane * 4);
    const float f0 = __uint_as_float(raw.x << 16);
    const float f1 = __uint_as_float(raw.x & 0xffff0000u);
    const float f2 = __uint_as_float(raw.y << 16);
    const float f3 = __uint_as_float(raw.y & 0xffff0000u);

    float* dst = agg + (size_t)r * N_HID + lane * 4;
    atomicAdd(dst + 0, v * f0);
    atomicAdd(dst + 1, v * f1);
    atomicAdd(dst + 2, v * f2);
    atomicAdd(dst + 3, v * f3);
}

// ---------------- PReLU in place (+ optional per-feature column sums) -------
#define NPB 256
__global__ __launch_bounds__(256) void prelu_colsum(
    float* __restrict__ agg, const float* __restrict__ pa,
    float* __restrict__ colsum, int N, int do_sum)
{
    const int j = threadIdx.x;
    const float a = pa[0];
    const int n0 = blockIdx.x * NPB;
    const int n1 = min(n0 + NPB, N);
    float sum = 0.f;
    for (int n = n0; n < n1; n++) {
        float vv = agg[(size_t)n * N_HID + j];
        vv = (vv >= 0.f) ? vv : a * vv;
        agg[(size_t)n * N_HID + j] = vv;
        sum += vv;
    }
    if (do_sum) atomicAdd(&colsum[j], sum);
}

// ---------------- v = bil_w @ sigmoid(colsum/N), single block --------------
__global__ __launch_bounds__(256) void compute_v(
    const float* __restrict__ colsum, const float* __restrict__ bilw,
    float* __restrict__ vbuf, int N)
{
    __shared__ float s[N_HID];
    const int t = threadIdx.x;
    const float mean = colsum[t] / (float)N;
    s[t] = 1.f / (1.f + expf(-mean));
    __syncthreads();
    float acc = 0.f;
    #pragma unroll 4
    for (int g = 0; g < N_HID; g++) acc += bilw[t * N_HID + g] * s[g];
    vbuf[t] = acc;
}

// ---------------- score[n] = dot(h[n], v) + bil_b, one wave per node -------
__global__ __launch_bounds__(256) void score_kernel(
    const float* __restrict__ hpost, const float* __restrict__ vbuf,
    const float* __restrict__ bilb, float* __restrict__ out, int N)
{
    __shared__ float vs[N_HID];
    if (threadIdx.x < N_HID) vs[threadIdx.x] = vbuf[threadIdx.x];
    __syncthreads();
    const int n = blockIdx.x * 4 + (threadIdx.x >> 6);
    if (n >= N) return;
    const int lane = threadIdx.x & 63;
    const float4 hv = *(const float4*)(hpost + (size_t)n * N_HID + lane * 4);
    const float4 vv = *(const float4*)(&vs[lane * 4]);
    float p = hv.x * vv.x + hv.y * vv.y + hv.z * vv.z + hv.w * vv.w;
    #pragma unroll
    for (int off = 32; off > 0; off >>= 1) p += __shfl_down(p, off);
    if (lane == 0) out[n] = p + bilb[0];
}

extern "C" void kernel_launch(void* const* d_in, const int* in_sizes, int n_in,
                              void* d_out, int out_size, void* d_ws, size_t ws_size,
                              hipStream_t stream)
{
    const float* x1     = (const float*)d_in[0];
    const float* x2     = (const float*)d_in[1];
    const float* evals  = (const float*)d_in[2];
    const float* fc_w   = (const float*)d_in[3];
    const float* fc_b   = (const float*)d_in[4];
    const float* prelua = (const float*)d_in[5];
    const float* bil_w  = (const float*)d_in[6];
    const float* bil_b  = (const float*)d_in[7];
    const int*   eidx   = (const int*)d_in[8];
    const int*   erow   = eidx;             // edge_index[0]
    const int*   ecol   = eidx + N_EDGES;   // edge_index[1]
    float* out = (float*)d_out;

    // workspace layout
    char* ws = (char*)d_ws;
    __hip_bfloat16* h_bf = (__hip_bfloat16*)ws;                    // 51.2 MB
    float* agg    = (float*)(ws + (size_t)56 * 1024 * 1024);       // 102.4 MB
    float* colsum = (float*)(ws + (size_t)162 * 1024 * 1024);      // 1 KB
    float* vbuf   = colsum + N_HID;

    const dim3 gemm_grid((N_NODES + TILE - 1) / TILE, N_HID / TILE);
    const int spmm_blocks  = (N_EDGES + 3) / 4;
    const int prelu_blocks = (N_NODES + NPB - 1) / NPB;
    const int score_blocks = (N_NODES + 3) / 4;

    // ---------------- GCN 1 ----------------
    hipMemsetAsync(agg, 0, (size_t)N_NODES * N_HID * sizeof(float), stream);
    hipMemsetAsync(colsum, 0, N_HID * sizeof(float), stream);
    gemm_fc<<<gemm_grid, 256, 0, stream>>>(x1, fc_w, fc_b, h_bf, N_NODES);
    spmm_scatter<<<spmm_blocks, 256, 0, stream>>>(h_bf, erow, ecol, evals, agg, N_EDGES);
    prelu_colsum<<<prelu_blocks, 256, 0, stream>>>(agg, prelua, colsum, N_NODES, 1);
    compute_v<<<1, 256, 0, stream>>>(colsum, bil_w, vbuf, N_NODES);
    score_kernel<<<score_blocks, 256, 0, stream>>>(agg, vbuf, bil_b, out, N_NODES);

    // ---------------- GCN 2 (reuses h_bf / agg) ----------------
    hipMemsetAsync(agg, 0, (size_t)N_NODES * N_HID * sizeof(float), stream);
    gemm_fc<<<gemm_grid, 256, 0, stream>>>(x2, fc_w, fc_b, h_bf, N_NODES);
    spmm_scatter<<<spmm_blocks, 256, 0, stream>>>(h_bf, erow, ecol, evals, agg, N_EDGES);
    prelu_colsum<<<prelu_blocks, 256, 0, stream>>>(agg, prelua, colsum, N_NODES, 0);
    score_kernel<<<score_blocks, 256, 0, stream>>>(agg, vbuf, bil_b, out + N_NODES, N_NODES);
}

// Round 2
// 2130.987 us; speedup vs baseline: 10.4603x; 10.4603x over previous
//
#include <hip/hip_runtime.h>
#include <hip/hip_bf16.h>

#define N_NODES 100000
#define N_FEAT  512
#define N_HID   256
#define N_EDGES 3200000

// ---------------- FC GEMM: h[n,j] = sum_f X[n,f]*W[j,f] + b[j], out bf16 ----
#define TILE 64
#define KT   16

__global__ __launch_bounds__(256) void gemm_fc(
    const float* __restrict__ X, const float* __restrict__ W,
    const float* __restrict__ bias, __hip_bfloat16* __restrict__ Hout, int N)
{
    __shared__ float Xs[KT][TILE + 4];
    __shared__ float Ws[KT][TILE + 4];

    const int tid = threadIdx.x;
    const int tx = tid & 15;
    const int ty = tid >> 4;
    const int n0 = blockIdx.x * TILE;
    const int j0 = blockIdx.y * TILE;

    const int lrow = tid >> 2;
    const int lk   = (tid & 3) * 4;

    const int gn = n0 + lrow;
    const bool xok = gn < N;
    const float* xp = X + (size_t)(xok ? gn : 0) * N_FEAT + lk;
    const float* wp = W + (size_t)(j0 + lrow) * N_FEAT + lk;

    float acc[4][4] = {{0.f}};

    for (int k0 = 0; k0 < N_FEAT; k0 += KT) {
        float4 xv = xok ? *(const float4*)(xp + k0) : make_float4(0.f, 0.f, 0.f, 0.f);
        float4 wv = *(const float4*)(wp + k0);
        __syncthreads();
        Xs[lk + 0][lrow] = xv.x; Xs[lk + 1][lrow] = xv.y;
        Xs[lk + 2][lrow] = xv.z; Xs[lk + 3][lrow] = xv.w;
        Ws[lk + 0][lrow] = wv.x; Ws[lk + 1][lrow] = wv.y;
        Ws[lk + 2][lrow] = wv.z; Ws[lk + 3][lrow] = wv.w;
        __syncthreads();
        #pragma unroll
        for (int kk = 0; kk < KT; kk++) {
            const float4 av = *(const float4*)(&Xs[kk][ty * 4]);
            const float4 bv = *(const float4*)(&Ws[kk][tx * 4]);
            const float a0 = av.x, a1 = av.y, a2 = av.z, a3 = av.w;
            const float b0 = bv.x, b1 = bv.y, b2 = bv.z, b3 = bv.w;
            acc[0][0] += a0 * b0; acc[0][1] += a0 * b1; acc[0][2] += a0 * b2; acc[0][3] += a0 * b3;
            acc[1][0] += a1 * b0; acc[1][1] += a1 * b1; acc[1][2] += a1 * b2; acc[1][3] += a1 * b3;
            acc[2][0] += a2 * b0; acc[2][1] += a2 * b1; acc[2][2] += a2 * b2; acc[2][3] += a2 * b3;
            acc[3][0] += a3 * b0; acc[3][1] += a3 * b1; acc[3][2] += a3 * b2; acc[3][3] += a3 * b3;
        }
    }

    #pragma unroll
    for (int i = 0; i < 4; i++) {
        const int gn2 = n0 + ty * 4 + i;
        if (gn2 >= N) continue;
        #pragma unroll
        for (int j = 0; j < 4; j++) {
            const int gj = j0 + tx * 4 + j;
            Hout[(size_t)gn2 * N_HID + gj] = __float2bfloat16(acc[i][j] + bias[gj]);
        }
    }
}

// ---------------- CSR build ------------------------------------------------
__global__ __launch_bounds__(256) void histogram_rows(
    const int* __restrict__ rows, int* __restrict__ counts, int E)
{
    const int e = blockIdx.x * 256 + threadIdx.x;
    if (e < E) atomicAdd(&counts[rows[e]], 1);
}

// single-block exclusive scan of counts[0..n-1] -> offsets[0..n]
#define SCAN_T 1024
__global__ __launch_bounds__(SCAN_T) void scan_kernel(
    const int* __restrict__ counts, int* __restrict__ offsets, int n)
{
    const int tid = threadIdx.x;
    const int seg = (n + SCAN_T - 1) / SCAN_T;
    const int s0 = tid * seg;
    const int s1 = min(s0 + seg, n);

    int sum = 0;
    for (int i = s0; i < s1; i++) sum += counts[i];

    __shared__ int wsum[SCAN_T / 64];
    const int lane = tid & 63;
    const int wid  = tid >> 6;
    int v = sum;
    #pragma unroll
    for (int off = 1; off < 64; off <<= 1) {
        int t = __shfl_up(v, off);
        if (lane >= off) v += t;
    }
    if (lane == 63) wsum[wid] = v;
    __syncthreads();
    if (wid == 0 && lane < SCAN_T / 64) {
        int w = wsum[lane];
        #pragma unroll
        for (int off = 1; off < SCAN_T / 64; off <<= 1) {
            int t = __shfl_up(w, off);
            if (lane >= off) w += t;
        }
        wsum[lane] = w;
    }
    __syncthreads();
    int base = v - sum + (wid > 0 ? wsum[wid - 1] : 0);

    int run = base;
    for (int i = s0; i < s1; i++) {
        const int c = counts[i];
        offsets[i] = run;
        run += c;
    }
    if (tid == SCAN_T - 1) offsets[n] = run;
}

__global__ __launch_bounds__(256) void scatter_edges(
    const int* __restrict__ rows, const int* __restrict__ cols,
    const float* __restrict__ ev, int* __restrict__ cursor,
    int* __restrict__ ccol, float* __restrict__ cval, int E)
{
    const int e = blockIdx.x * 256 + threadIdx.x;
    if (e >= E) return;
    const int pos = atomicAdd(&cursor[rows[e]], 1);
    ccol[pos] = cols[e];
    cval[pos] = ev[e];
}

// ---------------- per-row aggregation --------------------------------------
__device__ __forceinline__ void bf4_unpack(uint2 raw, float& f0, float& f1,
                                           float& f2, float& f3)
{
    f0 = __uint_as_float(raw.x << 16);
    f1 = __uint_as_float(raw.x & 0xffff0000u);
    f2 = __uint_as_float(raw.y << 16);
    f3 = __uint_as_float(raw.y & 0xffff0000u);
}

__device__ __forceinline__ uint2 bf4_pack(float f0, float f1, float f2, float f3)
{
    union { unsigned short u[4]; uint2 v; } pk;
    __hip_bfloat16 b0 = __float2bfloat16(f0);
    __hip_bfloat16 b1 = __float2bfloat16(f1);
    __hip_bfloat16 b2 = __float2bfloat16(f2);
    __hip_bfloat16 b3 = __float2bfloat16(f3);
    pk.u[0] = *(unsigned short*)&b0; pk.u[1] = *(unsigned short*)&b1;
    pk.u[2] = *(unsigned short*)&b2; pk.u[3] = *(unsigned short*)&b3;
    return pk.v;
}

// GCN1: aggregate -> PReLU -> store h_post bf16
__global__ __launch_bounds__(256) void agg_rows_1(
    const __hip_bfloat16* __restrict__ H, const int* __restrict__ offsets,
    const int* __restrict__ ccol, const float* __restrict__ cval,
    const float* __restrict__ pa, __hip_bfloat16* __restrict__ hpost, int N)
{
    const int row = blockIdx.x * 4 + (threadIdx.x >> 6);
    if (row >= N) return;
    const int lane = threadIdx.x & 63;
    const int beg = offsets[row], end = offsets[row + 1];
    const unsigned short* Hs = (const unsigned short*)H;

    float a0 = 0.f, a1 = 0.f, a2 = 0.f, a3 = 0.f;
    int e = beg;
    for (; e + 1 < end; e += 2) {
        const int c0 = ccol[e], c1 = ccol[e + 1];
        const float v0 = cval[e], v1 = cval[e + 1];
        const uint2 r0 = *(const uint2*)(Hs + (size_t)c0 * N_HID + lane * 4);
        const uint2 r1 = *(const uint2*)(Hs + (size_t)c1 * N_HID + lane * 4);
        float f0, f1, f2, f3, g0, g1, g2, g3;
        bf4_unpack(r0, f0, f1, f2, f3);
        bf4_unpack(r1, g0, g1, g2, g3);
        a0 += v0 * f0 + v1 * g0; a1 += v0 * f1 + v1 * g1;
        a2 += v0 * f2 + v1 * g2; a3 += v0 * f3 + v1 * g3;
    }
    if (e < end) {
        const int c0 = ccol[e];
        const float v0 = cval[e];
        const uint2 r0 = *(const uint2*)(Hs + (size_t)c0 * N_HID + lane * 4);
        float f0, f1, f2, f3;
        bf4_unpack(r0, f0, f1, f2, f3);
        a0 += v0 * f0; a1 += v0 * f1; a2 += v0 * f2; a3 += v0 * f3;
    }
    const float al = pa[0];
    a0 = (a0 >= 0.f) ? a0 : al * a0;
    a1 = (a1 >= 0.f) ? a1 : al * a1;
    a2 = (a2 >= 0.f) ? a2 : al * a2;
    a3 = (a3 >= 0.f) ? a3 : al * a3;
    *(uint2*)((unsigned short*)hpost + (size_t)row * N_HID + lane * 4) =
        bf4_pack(a0, a1, a2, a3);
}

// GCN2: aggregate -> PReLU -> dot(v) -> score (no h_post materialization)
__global__ __launch_bounds__(256) void agg_rows_2(
    const __hip_bfloat16* __restrict__ H, const int* __restrict__ offsets,
    const int* __restrict__ ccol, const float* __restrict__ cval,
    const float* __restrict__ pa, const float* __restrict__ vbuf,
    const float* __restrict__ bilb, float* __restrict__ out, int N)
{
    __shared__ float vs[N_HID];
    vs[threadIdx.x] = vbuf[threadIdx.x];
    __syncthreads();

    const int row = blockIdx.x * 4 + (threadIdx.x >> 6);
    if (row >= N) return;
    const int lane = threadIdx.x & 63;
    const int beg = offsets[row], end = offsets[row + 1];
    const unsigned short* Hs = (const unsigned short*)H;

    float a0 = 0.f, a1 = 0.f, a2 = 0.f, a3 = 0.f;
    int e = beg;
    for (; e + 1 < end; e += 2) {
        const int c0 = ccol[e], c1 = ccol[e + 1];
        const float v0 = cval[e], v1 = cval[e + 1];
        const uint2 r0 = *(const uint2*)(Hs + (size_t)c0 * N_HID + lane * 4);
        const uint2 r1 = *(const uint2*)(Hs + (size_t)c1 * N_HID + lane * 4);
        float f0, f1, f2, f3, g0, g1, g2, g3;
        bf4_unpack(r0, f0, f1, f2, f3);
        bf4_unpack(r1, g0, g1, g2, g3);
        a0 += v0 * f0 + v1 * g0; a1 += v0 * f1 + v1 * g1;
        a2 += v0 * f2 + v1 * g2; a3 += v0 * f3 + v1 * g3;
    }
    if (e < end) {
        const int c0 = ccol[e];
        const float v0 = cval[e];
        const uint2 r0 = *(const uint2*)(Hs + (size_t)c0 * N_HID + lane * 4);
        float f0, f1, f2, f3;
        bf4_unpack(r0, f0, f1, f2, f3);
        a0 += v0 * f0; a1 += v0 * f1; a2 += v0 * f2; a3 += v0 * f3;
    }
    const float al = pa[0];
    a0 = (a0 >= 0.f) ? a0 : al * a0;
    a1 = (a1 >= 0.f) ? a1 : al * a1;
    a2 = (a2 >= 0.f) ? a2 : al * a2;
    a3 = (a3 >= 0.f) ? a3 : al * a3;

    float p = a0 * vs[lane * 4 + 0] + a1 * vs[lane * 4 + 1] +
              a2 * vs[lane * 4 + 2] + a3 * vs[lane * 4 + 3];
    #pragma unroll
    for (int off = 32; off > 0; off >>= 1) p += __shfl_down(p, off);
    if (lane == 0) out[row] = p + bilb[0];
}

// ---------------- column sums of bf16 h_post -------------------------------
#define NPB 256
__global__ __launch_bounds__(256) void colsum_kernel(
    const __hip_bfloat16* __restrict__ hpost, float* __restrict__ colsum, int N)
{
    const int j = threadIdx.x;
    const int n0 = blockIdx.x * NPB;
    const int n1 = min(n0 + NPB, N);
    float s = 0.f;
    for (int n = n0; n < n1; n++)
        s += __bfloat162float(hpost[(size_t)n * N_HID + j]);
    atomicAdd(&colsum[j], s);
}

// ---------------- v = bil_w @ sigmoid(colsum/N) ----------------------------
__global__ __launch_bounds__(256) void compute_v(
    const float* __restrict__ colsum, const float* __restrict__ bilw,
    float* __restrict__ vbuf, int N)
{
    __shared__ float s[N_HID];
    const int t = threadIdx.x;
    const float mean = colsum[t] / (float)N;
    s[t] = 1.f / (1.f + expf(-mean));
    __syncthreads();
    float acc = 0.f;
    #pragma unroll 4
    for (int g = 0; g < N_HID; g++) acc += bilw[t * N_HID + g] * s[g];
    vbuf[t] = acc;
}

// ---------------- score_1: dot(h_post bf16, v) -----------------------------
__global__ __launch_bounds__(256) void score_kernel(
    const __hip_bfloat16* __restrict__ hpost, const float* __restrict__ vbuf,
    const float* __restrict__ bilb, float* __restrict__ out, int N)
{
    __shared__ float vs[N_HID];
    vs[threadIdx.x] = vbuf[threadIdx.x];
    __syncthreads();
    const int n = blockIdx.x * 4 + (threadIdx.x >> 6);
    if (n >= N) return;
    const int lane = threadIdx.x & 63;
    const uint2 raw = *(const uint2*)((const unsigned short*)hpost +
                                      (size_t)n * N_HID + lane * 4);
    float f0, f1, f2, f3;
    bf4_unpack(raw, f0, f1, f2, f3);
    float p = f0 * vs[lane * 4 + 0] + f1 * vs[lane * 4 + 1] +
              f2 * vs[lane * 4 + 2] + f3 * vs[lane * 4 + 3];
    #pragma unroll
    for (int off = 32; off > 0; off >>= 1) p += __shfl_down(p, off);
    if (lane == 0) out[n] = p + bilb[0];
}

extern "C" void kernel_launch(void* const* d_in, const int* in_sizes, int n_in,
                              void* d_out, int out_size, void* d_ws, size_t ws_size,
                              hipStream_t stream)
{
    const float* x1     = (const float*)d_in[0];
    const float* x2     = (const float*)d_in[1];
    const float* evals  = (const float*)d_in[2];
    const float* fc_w   = (const float*)d_in[3];
    const float* fc_b   = (const float*)d_in[4];
    const float* prelua = (const float*)d_in[5];
    const float* bil_w  = (const float*)d_in[6];
    const float* bil_b  = (const float*)d_in[7];
    const int*   eidx   = (const int*)d_in[8];
    const int*   erow   = eidx;
    const int*   ecol   = eidx + N_EDGES;
    float* out = (float*)d_out;

    // workspace layout (bytes)
    char* ws = (char*)d_ws;
    __hip_bfloat16* h_bf   = (__hip_bfloat16*)(ws);                         // 51.2 MB
    __hip_bfloat16* hpost1 = (__hip_bfloat16*)(ws + (size_t)52 * 1000000);  // 51.2 MB
    int*   ccol   = (int*)  (ws + (size_t)104 * 1000000);                   // 12.8 MB
    float* cval   = (float*)(ws + (size_t)117 * 1000000);                   // 12.8 MB
    int*   counts = (int*)  (ws + (size_t)130 * 1000000);                   // 400 KB
    int*   offs   = (int*)  (ws + (size_t)131 * 1000000);                   // 400 KB + 4
    int*   cursor = (int*)  (ws + (size_t)132 * 1000000);                   // 400 KB
    float* colsum = (float*)(ws + (size_t)133 * 1000000);                   // 1 KB
    float* vbuf   = colsum + N_HID;

    const dim3 gemm_grid((N_NODES + TILE - 1) / TILE, N_HID / TILE);
    const int eblocks   = (N_EDGES + 255) / 256;
    const int rowblocks = (N_NODES + 3) / 4;
    const int csblocks  = (N_NODES + NPB - 1) / NPB;

    // ---- CSR build (shared by both GCNs) ----
    hipMemsetAsync(counts, 0, N_NODES * sizeof(int), stream);
    hipMemsetAsync(colsum, 0, N_HID * sizeof(float), stream);
    histogram_rows<<<eblocks, 256, 0, stream>>>(erow, counts, N_EDGES);
    scan_kernel<<<1, SCAN_T, 0, stream>>>(counts, offs, N_NODES);
    hipMemcpyAsync(cursor, offs, N_NODES * sizeof(int),
                   hipMemcpyDeviceToDevice, stream);
    scatter_edges<<<eblocks, 256, 0, stream>>>(erow, ecol, evals, cursor,
                                               ccol, cval, N_EDGES);

    // ---- GCN 1 ----
    gemm_fc<<<gemm_grid, 256, 0, stream>>>(x1, fc_w, fc_b, h_bf, N_NODES);
    agg_rows_1<<<rowblocks, 256, 0, stream>>>(h_bf, offs, ccol, cval, prelua,
                                              hpost1, N_NODES);
    colsum_kernel<<<csblocks, 256, 0, stream>>>(hpost1, colsum, N_NODES);
    compute_v<<<1, 256, 0, stream>>>(colsum, bil_w, vbuf, N_NODES);
    score_kernel<<<rowblocks, 256, 0, stream>>>(hpost1, vbuf, bil_b, out, N_NODES);

    // ---- GCN 2 (reuses h_bf, CSR; fused score) ----
    gemm_fc<<<gemm_grid, 256, 0, stream>>>(x2, fc_w, fc_b, h_bf, N_NODES);
    agg_rows_2<<<rowblocks, 256, 0, stream>>>(h_bf, offs, ccol, cval, prelua,
                                              vbuf, bil_b, out + N_NODES, N_NODES);
}

// Round 3
// 1518.518 us; speedup vs baseline: 14.6792x; 1.4033x over previous
//
#include <hip/hip_runtime.h>
#include <hip/hip_bf16.h>

#define N_NODES 100000
#define N_FEAT  512
#define N_HID   256
#define N_EDGES 3200000

typedef __attribute__((ext_vector_type(8))) short bf16x8;
typedef __attribute__((ext_vector_type(4))) float f32x4;

__device__ __forceinline__ unsigned short bfu(float f)
{
    __hip_bfloat16 b = __float2bfloat16(f);
    return *(unsigned short*)&b;
}

__device__ __forceinline__ void llds16(const void* g, void* l)
{
    __builtin_amdgcn_global_load_lds(
        (const __attribute__((address_space(1))) unsigned int*)g,
        (__attribute__((address_space(3))) unsigned int*)l,
        16, 0, 0);
}

// ---------------- fp32 -> bf16 convert (for W) -----------------------------
__global__ __launch_bounds__(256) void convert_bf16_kernel(
    const float* __restrict__ in, unsigned short* __restrict__ outp, int n8)
{
    const int i = blockIdx.x * 256 + threadIdx.x;
    if (i >= n8) return;
    const float4 v0 = *(const float4*)(in + (size_t)i * 8);
    const float4 v1 = *(const float4*)(in + (size_t)i * 8 + 4);
    union { unsigned short s[8]; uint4 u; } pk;
    pk.s[0] = bfu(v0.x); pk.s[1] = bfu(v0.y); pk.s[2] = bfu(v0.z); pk.s[3] = bfu(v0.w);
    pk.s[4] = bfu(v1.x); pk.s[5] = bfu(v1.y); pk.s[6] = bfu(v1.z); pk.s[7] = bfu(v1.w);
    *(uint4*)(outp + (size_t)i * 8) = pk.u;
}

// ---------------- MFMA GEMM: h[n,j] = sum_k X[n,k]*W[j,k] + b[j] -----------
// BM=64 nodes, BN=256 (full H, X read once), BK=32. 4 waves, each 64x64.
#define BM 64
#define BN 256
#define BK 32

__global__ __launch_bounds__(256) void gemm_mfma(
    const float* __restrict__ X, const unsigned short* __restrict__ Wb,
    const float* __restrict__ bias, unsigned short* __restrict__ Hout, int N)
{
    __shared__ unsigned short As[BM * BK];   // [64][32] bf16, row-major
    __shared__ unsigned short Bs[BN * BK];   // [256][32] bf16, row-major

    const int tid  = threadIdx.x;
    const int wave = tid >> 6;
    const int lane = tid & 63;
    const int m0   = blockIdx.x * BM;

    // A staging: thread t -> row t>>2, k-chunk (t&3)*8 (8 fp32 -> 8 bf16)
    int arow = m0 + (tid >> 2);
    if (arow >= N) arow = N - 1;
    const float* ag = X + (size_t)arow * N_FEAT + (tid & 3) * 8;
    unsigned short* a_dst = As + tid * 8;   // byte offset tid*16 == row*64 + kp*16

    // B staging via global_load_lds: chunk c = i*256+tid -> j=c>>2, kp=c&3
    const unsigned short* bg = Wb + (size_t)(tid >> 2) * N_FEAT + (tid & 3) * 8;

    // fragment read pointers
    const unsigned short* ap = As + (lane & 15) * BK + (lane >> 4) * 8;
    const unsigned short* bp = Bs + ((size_t)(wave * 64 + (lane & 15))) * BK + (lane >> 4) * 8;

    f32x4 acc[4][4] = {};

    for (int k0 = 0; k0 < N_FEAT; k0 += BK) {
        if (k0) __syncthreads();   // previous compute done, safe to overwrite
        #pragma unroll
        for (int i = 0; i < 4; i++)
            llds16(bg + (size_t)i * 64 * N_FEAT + k0, Bs + ((size_t)(i * 256 + tid)) * 8);
        const float4 x0 = *(const float4*)(ag + k0);
        const float4 x1 = *(const float4*)(ag + k0 + 4);
        union { unsigned short s[8]; uint4 u; } pk;
        pk.s[0] = bfu(x0.x); pk.s[1] = bfu(x0.y); pk.s[2] = bfu(x0.z); pk.s[3] = bfu(x0.w);
        pk.s[4] = bfu(x1.x); pk.s[5] = bfu(x1.y); pk.s[6] = bfu(x1.z); pk.s[7] = bfu(x1.w);
        *(uint4*)a_dst = pk.u;
        __syncthreads();           // staging (incl. global_load_lds) visible

        bf16x8 af[4], bfr[4];
        #pragma unroll
        for (int mt = 0; mt < 4; mt++) af[mt] = *(const bf16x8*)(ap + mt * 16 * BK);
        #pragma unroll
        for (int nt = 0; nt < 4; nt++) bfr[nt] = *(const bf16x8*)(bp + nt * 16 * BK);
        #pragma unroll
        for (int mt = 0; mt < 4; mt++)
            #pragma unroll
            for (int nt = 0; nt < 4; nt++)
                acc[mt][nt] = __builtin_amdgcn_mfma_f32_16x16x32_bf16(
                    af[mt], bfr[nt], acc[mt][nt], 0, 0, 0);
    }

    // epilogue: C/D layout col=lane&15, row=(lane>>4)*4+reg
    const int q  = lane >> 4;
    const int c0 = lane & 15;
    float bcol[4];
    #pragma unroll
    for (int nt = 0; nt < 4; nt++) bcol[nt] = bias[wave * 64 + nt * 16 + c0];
    #pragma unroll
    for (int mt = 0; mt < 4; mt++) {
        #pragma unroll
        for (int r = 0; r < 4; r++) {
            const int row = m0 + mt * 16 + q * 4 + r;
            if (row >= N) continue;
            #pragma unroll
            for (int nt = 0; nt < 4; nt++) {
                const int col = wave * 64 + nt * 16 + c0;
                Hout[(size_t)row * N_HID + col] = bfu(acc[mt][nt][r] + bcol[nt]);
            }
        }
    }
}

// ---------------- CSR build ------------------------------------------------
__global__ __launch_bounds__(256) void histogram_rows(
    const int* __restrict__ rows, int* __restrict__ counts, int E)
{
    const int e = blockIdx.x * 256 + threadIdx.x;
    if (e < E) atomicAdd(&counts[rows[e]], 1);
}

#define SCAN_T 1024
__global__ __launch_bounds__(SCAN_T) void scan_kernel(
    const int* __restrict__ counts, int* __restrict__ offsets, int n)
{
    const int tid = threadIdx.x;
    const int seg = (n + SCAN_T - 1) / SCAN_T;
    const int s0 = tid * seg;
    const int s1 = min(s0 + seg, n);

    int sum = 0;
    for (int i = s0; i < s1; i++) sum += counts[i];

    __shared__ int wsum[SCAN_T / 64];
    const int lane = tid & 63;
    const int wid  = tid >> 6;
    int v = sum;
    #pragma unroll
    for (int off = 1; off < 64; off <<= 1) {
        int t = __shfl_up(v, off);
        if (lane >= off) v += t;
    }
    if (lane == 63) wsum[wid] = v;
    __syncthreads();
    if (wid == 0 && lane < SCAN_T / 64) {
        int w = wsum[lane];
        #pragma unroll
        for (int off = 1; off < SCAN_T / 64; off <<= 1) {
            int t = __shfl_up(w, off);
            if (lane >= off) w += t;
        }
        wsum[lane] = w;
    }
    __syncthreads();
    int base = v - sum + (wid > 0 ? wsum[wid - 1] : 0);

    int run = base;
    for (int i = s0; i < s1; i++) {
        const int c = counts[i];
        offsets[i] = run;
        run += c;
    }
    if (tid == SCAN_T - 1) offsets[n] = run;
}

__global__ __launch_bounds__(256) void scatter_edges(
    const int* __restrict__ rows, const int* __restrict__ cols,
    const float* __restrict__ ev, int* __restrict__ cursor,
    int* __restrict__ ccol, float* __restrict__ cval, int E)
{
    const int e = blockIdx.x * 256 + threadIdx.x;
    if (e >= E) return;
    const int pos = atomicAdd(&cursor[rows[e]], 1);
    ccol[pos] = cols[e];
    cval[pos] = ev[e];
}

// ---------------- per-row aggregation --------------------------------------
__device__ __forceinline__ void bf4_unpack(uint2 raw, float& f0, float& f1,
                                           float& f2, float& f3)
{
    f0 = __uint_as_float(raw.x << 16);
    f1 = __uint_as_float(raw.x & 0xffff0000u);
    f2 = __uint_as_float(raw.y << 16);
    f3 = __uint_as_float(raw.y & 0xffff0000u);
}

__device__ __forceinline__ uint2 bf4_pack(float f0, float f1, float f2, float f3)
{
    union { unsigned short u[4]; uint2 v; } pk;
    pk.u[0] = bfu(f0); pk.u[1] = bfu(f1); pk.u[2] = bfu(f2); pk.u[3] = bfu(f3);
    return pk.v;
}

// GCN1: aggregate -> PReLU -> store h_post bf16
__global__ __launch_bounds__(256) void agg_rows_1(
    const __hip_bfloat16* __restrict__ H, const int* __restrict__ offsets,
    const int* __restrict__ ccol, const float* __restrict__ cval,
    const float* __restrict__ pa, __hip_bfloat16* __restrict__ hpost, int N)
{
    const int row = blockIdx.x * 4 + (threadIdx.x >> 6);
    if (row >= N) return;
    const int lane = threadIdx.x & 63;
    const int beg = offsets[row], end = offsets[row + 1];
    const unsigned short* Hs = (const unsigned short*)H;

    float a0 = 0.f, a1 = 0.f, a2 = 0.f, a3 = 0.f;
    int e = beg;
    for (; e + 1 < end; e += 2) {
        const int c0 = ccol[e], c1 = ccol[e + 1];
        const float v0 = cval[e], v1 = cval[e + 1];
        const uint2 r0 = *(const uint2*)(Hs + (size_t)c0 * N_HID + lane * 4);
        const uint2 r1 = *(const uint2*)(Hs + (size_t)c1 * N_HID + lane * 4);
        float f0, f1, f2, f3, g0, g1, g2, g3;
        bf4_unpack(r0, f0, f1, f2, f3);
        bf4_unpack(r1, g0, g1, g2, g3);
        a0 += v0 * f0 + v1 * g0; a1 += v0 * f1 + v1 * g1;
        a2 += v0 * f2 + v1 * g2; a3 += v0 * f3 + v1 * g3;
    }
    if (e < end) {
        const int c0 = ccol[e];
        const float v0 = cval[e];
        const uint2 r0 = *(const uint2*)(Hs + (size_t)c0 * N_HID + lane * 4);
        float f0, f1, f2, f3;
        bf4_unpack(r0, f0, f1, f2, f3);
        a0 += v0 * f0; a1 += v0 * f1; a2 += v0 * f2; a3 += v0 * f3;
    }
    const float al = pa[0];
    a0 = (a0 >= 0.f) ? a0 : al * a0;
    a1 = (a1 >= 0.f) ? a1 : al * a1;
    a2 = (a2 >= 0.f) ? a2 : al * a2;
    a3 = (a3 >= 0.f) ? a3 : al * a3;
    *(uint2*)((unsigned short*)hpost + (size_t)row * N_HID + lane * 4) =
        bf4_pack(a0, a1, a2, a3);
}

// GCN2: aggregate -> PReLU -> dot(v) -> score
__global__ __launch_bounds__(256) void agg_rows_2(
    const __hip_bfloat16* __restrict__ H, const int* __restrict__ offsets,
    const int* __restrict__ ccol, const float* __restrict__ cval,
    const float* __restrict__ pa, const float* __restrict__ vbuf,
    const float* __restrict__ bilb, float* __restrict__ out, int N)
{
    __shared__ float vs[N_HID];
    vs[threadIdx.x] = vbuf[threadIdx.x];
    __syncthreads();

    const int row = blockIdx.x * 4 + (threadIdx.x >> 6);
    if (row >= N) return;
    const int lane = threadIdx.x & 63;
    const int beg = offsets[row], end = offsets[row + 1];
    const unsigned short* Hs = (const unsigned short*)H;

    float a0 = 0.f, a1 = 0.f, a2 = 0.f, a3 = 0.f;
    int e = beg;
    for (; e + 1 < end; e += 2) {
        const int c0 = ccol[e], c1 = ccol[e + 1];
        const float v0 = cval[e], v1 = cval[e + 1];
        const uint2 r0 = *(const uint2*)(Hs + (size_t)c0 * N_HID + lane * 4);
        const uint2 r1 = *(const uint2*)(Hs + (size_t)c1 * N_HID + lane * 4);
        float f0, f1, f2, f3, g0, g1, g2, g3;
        bf4_unpack(r0, f0, f1, f2, f3);
        bf4_unpack(r1, g0, g1, g2, g3);
        a0 += v0 * f0 + v1 * g0; a1 += v0 * f1 + v1 * g1;
        a2 += v0 * f2 + v1 * g2; a3 += v0 * f3 + v1 * g3;
    }
    if (e < end) {
        const int c0 = ccol[e];
        const float v0 = cval[e];
        const uint2 r0 = *(const uint2*)(Hs + (size_t)c0 * N_HID + lane * 4);
        float f0, f1, f2, f3;
        bf4_unpack(r0, f0, f1, f2, f3);
        a0 += v0 * f0; a1 += v0 * f1; a2 += v0 * f2; a3 += v0 * f3;
    }
    const float al = pa[0];
    a0 = (a0 >= 0.f) ? a0 : al * a0;
    a1 = (a1 >= 0.f) ? a1 : al * a1;
    a2 = (a2 >= 0.f) ? a2 : al * a2;
    a3 = (a3 >= 0.f) ? a3 : al * a3;

    float p = a0 * vs[lane * 4 + 0] + a1 * vs[lane * 4 + 1] +
              a2 * vs[lane * 4 + 2] + a3 * vs[lane * 4 + 3];
    #pragma unroll
    for (int off = 32; off > 0; off >>= 1) p += __shfl_down(p, off);
    if (lane == 0) out[row] = p + bilb[0];
}

// ---------------- column sums of bf16 h_post -------------------------------
#define NPB 256
__global__ __launch_bounds__(256) void colsum_kernel(
    const __hip_bfloat16* __restrict__ hpost, float* __restrict__ colsum, int N)
{
    const int j = threadIdx.x;
    const int n0 = blockIdx.x * NPB;
    const int n1 = min(n0 + NPB, N);
    float s = 0.f;
    for (int n = n0; n < n1; n++)
        s += __bfloat162float(hpost[(size_t)n * N_HID + j]);
    atomicAdd(&colsum[j], s);
}

// ---------------- v = bil_w @ sigmoid(colsum/N) ----------------------------
__global__ __launch_bounds__(256) void compute_v(
    const float* __restrict__ colsum, const float* __restrict__ bilw,
    float* __restrict__ vbuf, int N)
{
    __shared__ float s[N_HID];
    const int t = threadIdx.x;
    const float mean = colsum[t] / (float)N;
    s[t] = 1.f / (1.f + expf(-mean));
    __syncthreads();
    float acc = 0.f;
    #pragma unroll 4
    for (int g = 0; g < N_HID; g++) acc += bilw[t * N_HID + g] * s[g];
    vbuf[t] = acc;
}

// ---------------- score_1: dot(h_post bf16, v) -----------------------------
__global__ __launch_bounds__(256) void score_kernel(
    const __hip_bfloat16* __restrict__ hpost, const float* __restrict__ vbuf,
    const float* __restrict__ bilb, float* __restrict__ out, int N)
{
    __shared__ float vs[N_HID];
    vs[threadIdx.x] = vbuf[threadIdx.x];
    __syncthreads();
    const int n = blockIdx.x * 4 + (threadIdx.x >> 6);
    if (n >= N) return;
    const int lane = threadIdx.x & 63;
    const uint2 raw = *(const uint2*)((const unsigned short*)hpost +
                                      (size_t)n * N_HID + lane * 4);
    float f0, f1, f2, f3;
    bf4_unpack(raw, f0, f1, f2, f3);
    float p = f0 * vs[lane * 4 + 0] + f1 * vs[lane * 4 + 1] +
              f2 * vs[lane * 4 + 2] + f3 * vs[lane * 4 + 3];
    #pragma unroll
    for (int off = 32; off > 0; off >>= 1) p += __shfl_down(p, off);
    if (lane == 0) out[n] = p + bilb[0];
}

extern "C" void kernel_launch(void* const* d_in, const int* in_sizes, int n_in,
                              void* d_out, int out_size, void* d_ws, size_t ws_size,
                              hipStream_t stream)
{
    const float* x1     = (const float*)d_in[0];
    const float* x2     = (const float*)d_in[1];
    const float* evals  = (const float*)d_in[2];
    const float* fc_w   = (const float*)d_in[3];
    const float* fc_b   = (const float*)d_in[4];
    const float* prelua = (const float*)d_in[5];
    const float* bil_w  = (const float*)d_in[6];
    const float* bil_b  = (const float*)d_in[7];
    const int*   eidx   = (const int*)d_in[8];
    const int*   erow   = eidx;
    const int*   ecol   = eidx + N_EDGES;
    float* out = (float*)d_out;

    // workspace layout (bytes)
    char* ws = (char*)d_ws;
    __hip_bfloat16* h_bf   = (__hip_bfloat16*)(ws);                         // 51.2 MB
    __hip_bfloat16* hpost1 = (__hip_bfloat16*)(ws + (size_t)52 * 1000000);  // 51.2 MB
    int*   ccol   = (int*)  (ws + (size_t)104 * 1000000);                   // 12.8 MB
    float* cval   = (float*)(ws + (size_t)117 * 1000000);                   // 12.8 MB
    unsigned short* wbf = (unsigned short*)(ws + (size_t)130 * 1000000);    // 262 KB
    int*   counts = (int*)  (ws + (size_t)131 * 1000000);                   // 400 KB
    int*   offs   = (int*)  (ws + (size_t)131500000);                       // 400 KB + 4
    int*   cursor = (int*)  (ws + (size_t)132 * 1000000);                   // 400 KB
    float* colsum = (float*)(ws + (size_t)132500000);                       // 1 KB
    float* vbuf   = colsum + N_HID;

    const int gemm_blocks = (N_NODES + BM - 1) / BM;
    const int eblocks   = (N_EDGES + 255) / 256;
    const int rowblocks = (N_NODES + 3) / 4;
    const int csblocks  = (N_NODES + NPB - 1) / NPB;

    // ---- CSR build (shared by both GCNs) + W convert ----
    hipMemsetAsync(counts, 0, N_NODES * sizeof(int), stream);
    hipMemsetAsync(colsum, 0, N_HID * sizeof(float), stream);
    histogram_rows<<<eblocks, 256, 0, stream>>>(erow, counts, N_EDGES);
    scan_kernel<<<1, SCAN_T, 0, stream>>>(counts, offs, N_NODES);
    hipMemcpyAsync(cursor, offs, N_NODES * sizeof(int),
                   hipMemcpyDeviceToDevice, stream);
    scatter_edges<<<eblocks, 256, 0, stream>>>(erow, ecol, evals, cursor,
                                               ccol, cval, N_EDGES);
    convert_bf16_kernel<<<(N_HID * N_FEAT / 8 + 255) / 256, 256, 0, stream>>>(
        fc_w, wbf, N_HID * N_FEAT / 8);

    // ---- GCN 1 ----
    gemm_mfma<<<gemm_blocks, 256, 0, stream>>>(x1, wbf, fc_b,
                                               (unsigned short*)h_bf, N_NODES);
    agg_rows_1<<<rowblocks, 256, 0, stream>>>(h_bf, offs, ccol, cval, prelua,
                                              hpost1, N_NODES);
    colsum_kernel<<<csblocks, 256, 0, stream>>>(hpost1, colsum, N_NODES);
    compute_v<<<1, 256, 0, stream>>>(colsum, bil_w, vbuf, N_NODES);
    score_kernel<<<rowblocks, 256, 0, stream>>>(hpost1, vbuf, bil_b, out, N_NODES);

    // ---- GCN 2 (reuses h_bf, CSR; fused score) ----
    gemm_mfma<<<gemm_blocks, 256, 0, stream>>>(x2, wbf, fc_b,
                                               (unsigned short*)h_bf, N_NODES);
    agg_rows_2<<<rowblocks, 256, 0, stream>>>(h_bf, offs, ccol, cval, prelua,
                                              vbuf, bil_b, out + N_NODES, N_NODES);
}